// Round 7
// baseline (87.080 us; speedup 1.0000x reference)
//
#include <hip/hip_runtime.h>
#include <hip/hip_bf16.h>
#include <math.h>

#define NS (16*256*64)   // 262144 samples
#define D 32
#define K 8

typedef __attribute__((ext_vector_type(8))) short bf16x8;
typedef __attribute__((ext_vector_type(8))) float f32x8;
typedef __attribute__((ext_vector_type(8))) __bf16 bf16v8;
typedef __attribute__((ext_vector_type(16))) float f32x16;

// ws float layout
#define WS_ENERGY   0
#define WS_COVDIAG  1
#define WS_DONE     2      // unsigned done-counter for k_energy's last-block finalize
#define WS_C        16     // 8 floats: mu^T Ainv mu per k
#define WS_COEF     24     // 8 floats: phi_k / sqrt(det(2pi cov))
#define WS_SG       32     // 8
#define WS_S1       64     // 256  [k*32+d]
#define WS_S2       1024   // 8192 [k*1024 + r*32 + c]
#define WS_FRAGA    9216   // 4096 floats = 16 frags x 64 lanes x 16B (Ainv bf16 A-operand frags)
#define WS_FRAGB    13312  // 512 floats  = 2 frags  x 64 lanes x 16B (b-rows stacked, A-operand)
#define WS_PART     16384
#define PART_STRIDE 8456   // 8192 S2 + 256 S1 + 8 SG

// compiler-path bf16 conversion (emits v_cvt_pk_bf16_f32 pairs)
__device__ __forceinline__ bf16x8 cvt8(f32x8 v) {
    union { bf16v8 h; bf16x8 s; } u;
    u.h = __builtin_convertvector(v, bf16v8);
    return u.s;
}
__device__ __forceinline__ short f2bf1(float f) {
    union { __bf16 h; short s; } u;
    u.h = (__bf16)f;
    return u.s;
}
// v_readlane_b32: 2-cyc VALU->SGPR broadcast, no LDS pipe (vs __shfl = ds_bpermute ~60cyc)
__device__ __forceinline__ float rdlane(float v, int lane) {
    return __uint_as_float(__builtin_amdgcn_readlane(__float_as_uint(v), lane));
}

// ---------------- Pass 1: moments via MFMA, direct global loads (no LDS, no barriers).
// grid nblk x 256 (4 waves; wave w owns k-pair {2w,2w+1}); all waves scan the block's chunks.
__global__ __launch_bounds__(256) void k_moments(const float* __restrict__ z,
                                                 const float* __restrict__ g,
                                                 float* __restrict__ part) {
    const int t   = threadIdx.x;
    const int w   = t >> 6;
    const int l   = t & 63;
    const int col = l & 31;
    const int nh  = l >> 5;
    const int k0  = 2 * w;

    f32x16 acc0 = {}, acc1 = {}, accA = {}, accB = {};
    float sga = 0.f, sgb = 0.f;
    bf16x8 ones;
#pragma unroll
    for (int j = 0; j < 8; j++) ones[j] = (short)0x3F80;   // bf16(1.0)

    for (int c = blockIdx.x; c < NS / 64; c += gridDim.x) {
        const int base = c * 64;
#pragma unroll
        for (int sc = 0; sc < 4; sc++) {
            const int n0 = base + sc * 16 + nh * 8;   // this half-wave's 8 samples
            f32x8 zv, p0, p1;
#pragma unroll
            for (int j = 0; j < 8; j++)
                zv[j] = z[(size_t)(n0 + j) * 32 + col];        // coalesced: 32 lanes = 32 cols
#pragma unroll
            for (int j = 0; j < 8; j++) {
                float2 gg = *(const float2*)(g + (size_t)(n0 + j) * 8 + k0);  // wave-uniform
                p0[j] = gg.x * zv[j];
                p1[j] = gg.y * zv[j];
                sga += gg.x;  sgb += gg.y;
            }
            bf16x8 af = cvt8(zv), b0 = cvt8(p0), b1 = cvt8(p1);
            acc0 = __builtin_amdgcn_mfma_f32_32x32x16_bf16(af,   b0, acc0, 0, 0, 0);
            acc1 = __builtin_amdgcn_mfma_f32_32x32x16_bf16(af,   b1, acc1, 0, 0, 0);
            accA = __builtin_amdgcn_mfma_f32_32x32x16_bf16(ones, b0, accA, 0, 0, 0);
            accB = __builtin_amdgcn_mfma_f32_32x32x16_bf16(ones, b1, accB, 0, 0, 0);
        }
    }
    // NOTE: each lane summed gamma over its own 8-sample half; halves are complementary
    sga += __shfl_xor(sga, 32);
    sgb += __shfl_xor(sgb, 32);

    float* pb = part + (size_t)blockIdx.x * PART_STRIDE;
#pragma unroll
    for (int r = 0; r < 16; r++) {
        int row = (r & 3) + 8 * (r >> 2) + 4 * nh;   // HW-verified C/D mapping (m74/m101)
        pb[(size_t)k0 * 1024 + row * 32 + col]       = acc0[r];
        pb[(size_t)(k0 + 1) * 1024 + row * 32 + col] = acc1[r];
    }
    // every row of accA/accB equals S1 (ones-A product); K=16 summed both sample-halves
    if (nh == 0) {
        pb[8192 + k0 * 32 + col]       = accA[0];
        pb[8192 + (k0 + 1) * 32 + col] = accB[0];
    }
    if (l == 0) { pb[8448 + k0] = sga; pb[8448 + k0 + 1] = sgb; }
}

// ---------------- Reduce partials -> ws S2/S1/SG. Parallel over BOTH axes.
// Also zeroes accumulators, done-counter, and FRAGB region.
__global__ __launch_bounds__(1024) void k_reduce(float* __restrict__ ws, int nblk) {
    __shared__ float red[16][64];
    const int t  = threadIdx.x;
    const int el = t & 63;
    const int bg = t >> 6;
    const int e  = blockIdx.x * 64 + el;
    const float* part = ws + WS_PART;
    float s = 0.0f;
    if (e < PART_STRIDE) {
        for (int b = bg; b < nblk; b += 16)
            s += part[(size_t)b * PART_STRIDE + e];
    }
    red[bg][el] = s;
    __syncthreads();
#pragma unroll
    for (int h = 8; h > 0; h >>= 1) {
        if (bg < h) red[bg][el] += red[bg + h][el];
        __syncthreads();
    }
    if (bg == 0 && e < PART_STRIDE) {
        float v = red[0][el];
        if (e < 8192)       ws[WS_S2 + e] = v;
        else if (e < 8448)  ws[WS_S1 + (e - 8192)] = v;
        else                ws[WS_SG + (e - 8448)] = v;
    }
    if (blockIdx.x == 0) {
        if (t < 512) ws[WS_FRAGB + t] = 0.0f;   // k_prep fills only rows k<8
        if (t == 0) {
            ws[WS_ENERGY] = 0.0f;
            ws[WS_COVDIAG] = 0.0f;
            ((unsigned*)ws)[WS_DONE] = 0u;
        }
    }
}

// ---------------- Pass 2: one single-wave block per matrix (grid = 8 x 64).
// Register-resident Gauss-Jordan on [A | I]; broadcasts via v_readlane (compile-time lanes).
__global__ __launch_bounds__(64) void k_prep(float* __restrict__ ws) {
    __shared__ float Am[32][33];   // Ainv
    __shared__ float mus[32];
    __shared__ float bLs[32];

    const int k   = blockIdx.x;
    const int l   = threadIdx.x;
    const int c32 = l & 31;
    const bool right = l >= 32;

    const float sgk = ws[WS_SG + k];
    if (l < 32) mus[l] = ws[WS_S1 + k * 32 + l] / sgk;
    __syncthreads();
    const float mc  = mus[c32];
    const float rsg = 1.0f / sgk;

    float x[32];
    float dval = 1.0f;
#pragma unroll
    for (int r = 0; r < 32; r++) {
        float v;
        if (right) {
            v = (r == c32) ? 1.0f : 0.0f;
        } else {
            v = ws[WS_S2 + k * 1024 + r * 32 + c32] * rsg - mus[r] * mc;
            if (r == c32) { v += 1.0e-6f + 1.0e-9f; dval = v; }
        }
        x[r] = v;
    }

    // cov_diag partial
    {
        float tdi = right ? 0.0f : 1.0f / dval;
#pragma unroll
        for (int m = 1; m < 64; m <<= 1) tdi += __shfl_xor(tdi, m);
        if (l == 0) atomicAdd(&ws[WS_COVDIAG], tdi);
    }

    // Gauss-Jordan, fully unrolled; pivot broadcasts via v_readlane (lane j is literal)
    float logdet = 0.0f;
#pragma unroll
    for (int j = 0; j < 32; j++) {
        float piv = rdlane(x[j], j);     // A[j][j]
        float rp  = 1.0f / piv;
        logdet += __logf(piv);
        x[j] *= rp;
#pragma unroll
        for (int r = 0; r < 32; r++) {
            if (r == j) continue;
            float m = rdlane(x[r], j);   // A[r][j] (pre-update this pivot)
            x[r] -= m * x[j];
        }
    }
    if (right) {
#pragma unroll
        for (int r = 0; r < 32; r++) Am[r][c32] = x[r];
    }
    __syncthreads();

    // coef_k = phi * exp(-(8*log(2pi) + 0.25*logdet(cov)))
    if (l == 0) {
        float phi = sgk / (float)NS;
        ws[WS_COEF + k] = phi * __expf(-(8.0f * 1.8378770664093453f + 0.25f * logdet));
    }

    // b = Ainv * mu
    if (l < 32) {
        float s = 0.0f;
#pragma unroll
        for (int c = 0; c < 32; c++) s += Am[c32][c] * mus[c];
        bLs[c32] = s;
    }
    __syncthreads();
    // c_k = mu . b
    {
        float cm = (l < 32) ? mus[c32] * bLs[c32] : 0.0f;
#pragma unroll
        for (int m = 1; m < 64; m <<= 1) cm += __shfl_xor(cm, m);
        if (l == 0) ws[WS_C + k] = cm;
    }

    // FRAGA: Ainv bf16 A-operand frags for this k
    {
        const int ph = l >> 5;
#pragma unroll
        for (int h = 0; h < 2; h++) {
            int r = c32, cb = ph * 8 + 16 * h;
            unsigned uu[4];
#pragma unroll
            for (int q = 0; q < 4; q++) {
                unsigned lo2 = (unsigned short)f2bf1(Am[r][cb + 2 * q]);
                unsigned hi2 = (unsigned short)f2bf1(Am[r][cb + 2 * q + 1]);
                uu[q] = lo2 | (hi2 << 16);
            }
            ((uint4*)(ws + WS_FRAGA))[(k * 2 + h) * 64 + l] = make_uint4(uu[0], uu[1], uu[2], uu[3]);
        }
        if (c32 == k) {
#pragma unroll
            for (int h = 0; h < 2; h++) {
                int cb = ph * 8 + 16 * h;
                unsigned uu[4];
#pragma unroll
                for (int q = 0; q < 4; q++) {
                    unsigned lo2 = (unsigned short)f2bf1(bLs[cb + 2 * q]);
                    unsigned hi2 = (unsigned short)f2bf1(bLs[cb + 2 * q + 1]);
                    uu[q] = lo2 | (hi2 << 16);
                }
                ((uint4*)(ws + WS_FRAGB))[h * 64 + l] = make_uint4(uu[0], uu[1], uu[2], uu[3]);
            }
        }
    }
}

// ---------------- Pass 3: energy via MFMA; last block finalizes d_out.
// grid 512 x 512 (8 waves), 2 chunks of 32 samples per wave.
__global__ __launch_bounds__(512) void k_energy(const float* __restrict__ z,
                                                float* __restrict__ ws,
                                                float* __restrict__ out) {
    __shared__ uint4 frg[1152];      // [0,1024): Ainv frags, [1024,1152): b frags
    __shared__ float redw[8];
    const int t   = threadIdx.x;
    const int w   = t >> 6;
    const int l   = t & 63;
    const int col = l & 31;
    const int nh  = l >> 5;

    for (int i = t; i < 1152; i += 512) frg[i] = ((const uint4*)(ws + WS_FRAGA))[i];
    float cf[8], cc[8];
#pragma unroll
    for (int k = 0; k < 8; k++) { cf[k] = ws[WS_COEF + k]; cc[k] = ws[WS_C + k]; }
    __syncthreads();

    float En = 0.0f;
    for (int ci = 0; ci < 2; ci++) {
        const int chunk = (blockIdx.x * 8 + w) * 2 + ci;
        const int n0 = chunk * 32;
        const float* zb = z + (size_t)(n0 + col) * 32 + nh * 8;
        float4 a0 = *(const float4*)(zb + 0);
        float4 a1 = *(const float4*)(zb + 4);
        float4 a2 = *(const float4*)(zb + 16);
        float4 a3 = *(const float4*)(zb + 20);
        f32x8 zlo = {a0.x,a0.y,a0.z,a0.w,a1.x,a1.y,a1.z,a1.w};
        f32x8 zhi = {a2.x,a2.y,a2.z,a2.w,a3.x,a3.y,a3.z,a3.w};
        bf16x8 b0 = cvt8(zlo), b1 = cvt8(zhi);
        float olo[4], ohi[4];
#pragma unroll
        for (int j = 0; j < 4; j++) {
            float mlo = nh ? zlo[j] : zlo[j + 4];
            float mhi = nh ? zhi[j] : zhi[j + 4];
            olo[j] = __shfl_xor(mlo, 32);
            ohi[j] = __shfl_xor(mhi, 32);
        }
        float zdot[16];
#pragma unroll
        for (int j = 0; j < 4; j++) {
            zdot[j]      = nh ? olo[j]     : zlo[j];
            zdot[4 + j]  = nh ? zlo[4 + j] : olo[j];
            zdot[8 + j]  = nh ? ohi[j]     : zhi[j];
            zdot[12 + j] = nh ? zhi[4 + j] : ohi[j];
        }
        f32x16 acc2 = {};
        {
            bf16x8 fb0 = *(const bf16x8*)&frg[1024 + l];
            bf16x8 fb1 = *(const bf16x8*)&frg[1024 + 64 + l];
            acc2 = __builtin_amdgcn_mfma_f32_32x32x16_bf16(fb0, b0, acc2, 0, 0, 0);
            acc2 = __builtin_amdgcn_mfma_f32_32x32x16_bf16(fb1, b1, acc2, 0, 0, 0);
        }
        float oth[4];
#pragma unroll
        for (int r = 0; r < 4; r++) oth[r] = __shfl_xor(acc2[r], 32);
        float pk[8];
#pragma unroll
        for (int k = 0; k < 8; k++) {
            bf16x8 fa0 = *(const bf16x8*)&frg[(k * 2 + 0) * 64 + l];
            bf16x8 fa1 = *(const bf16x8*)&frg[(k * 2 + 1) * 64 + l];
            f32x16 acc = {};
            acc = __builtin_amdgcn_mfma_f32_32x32x16_bf16(fa0, b0, acc, 0, 0, 0);
            acc = __builtin_amdgcn_mfma_f32_32x32x16_bf16(fa1, b1, acc, 0, 0, 0);
            float p = 0.0f;
#pragma unroll
            for (int r = 0; r < 16; r++) p += acc[r] * zdot[r];
            p += __shfl_xor(p, 32);
            pk[k] = p;
        }
        float ssum = 0.0f;
#pragma unroll
        for (int k = 0; k < 8; k++) {
            float d2 = (k < 4) ? (nh ? oth[k] : acc2[k]) : (nh ? acc2[k - 4] : oth[k - 4]);
            float E = pk[k] - 2.0f * d2 + cc[k];
            ssum += cf[k] * __expf(-0.5f * E);
        }
        En += -__logf(ssum + 1.0e-6f);
    }
    // wave reduce (6 shfl steps), then one barrier, then block sum
#pragma unroll
    for (int m = 1; m < 64; m <<= 1) En += __shfl_xor(En, m);
    if (l == 0) redw[w] = En;
    __syncthreads();
    if (t == 0) {
        float s = 0.0f;
#pragma unroll
        for (int i = 0; i < 8; i++) s += redw[i];
        atomicAdd(&ws[WS_ENERGY], s);
        __threadfence();
        unsigned old = atomicAdd((unsigned*)ws + WS_DONE, 1u);
        if (old == gridDim.x - 1) {   // last block finalizes
            float se = atomicAdd(&ws[WS_ENERGY], 0.0f);   // coherent read
            se = se * 0.5f / (float)NS;                   // each sample counted by 2 lane-halves
            if (!isfinite(se)) se = 0.0f;
            float cd = ws[WS_COVDIAG];
            if (!isfinite(cd)) cd = 0.0f;
            out[0] = 0.1f * se + 0.005f * cd;
        }
    }
}

extern "C" void kernel_launch(void* const* d_in, const int* in_sizes, int n_in,
                              void* d_out, int out_size, void* d_ws, size_t ws_size,
                              hipStream_t stream) {
    const float* z = (const float*)d_in[0];
    const float* g = (const float*)d_in[1];
    float* out = (float*)d_out;
    float* ws  = (float*)d_ws;

    long avail = (long)(ws_size / 4) - WS_PART;
    int nblk = (int)(avail / PART_STRIDE);
    if (nblk > 512) nblk = 512;
    if (nblk < 1)   nblk = 1;

    k_moments<<<nblk, 256, 0, stream>>>(z, g, ws + WS_PART);
    k_reduce<<<(PART_STRIDE + 63) / 64, 1024, 0, stream>>>(ws, nblk);
    k_prep<<<8, 64, 0, stream>>>(ws);
    k_energy<<<512, 512, 0, stream>>>(z, ws, out);
}

// Round 8
// 77.918 us; speedup vs baseline: 1.1176x; 1.1176x over previous
//
#include <hip/hip_runtime.h>
#include <hip/hip_bf16.h>
#include <math.h>

#define NS (16*256*64)   // 262144 samples
#define D 32
#define K 8

typedef __attribute__((ext_vector_type(8))) short bf16x8;
typedef __attribute__((ext_vector_type(8))) float f32x8;
typedef __attribute__((ext_vector_type(8))) __bf16 bf16v8;
typedef __attribute__((ext_vector_type(16))) float f32x16;

// ws float layout
#define WS_ENERGY   0
#define WS_COVDIAG  1
#define WS_DONE     2      // unsigned done-counter for k_energy's last-block finalize
#define WS_C        16     // 8 floats: mu^T Ainv mu per k
#define WS_COEF     24     // 8 floats: phi_k / sqrt(det(2pi cov))
#define WS_SG       32     // 8
#define WS_S1       64     // 256  [k*32+d]
#define WS_S2       1024   // 8192 [k*1024 + r*32 + c]
#define WS_FRAGA    9216   // 4096 floats = 16 frags x 64 lanes x 16B (Ainv bf16 A-operand frags)
#define WS_FRAGB    13312  // 512 floats  = 2 frags  x 64 lanes x 16B (b-rows stacked, A-operand)
#define WS_PART     16384
#define PART_STRIDE 8456   // 8192 S2 + 256 S1 + 8 SG

// compiler-path bf16 conversion (emits v_cvt_pk_bf16_f32 pairs)
__device__ __forceinline__ bf16x8 cvt8(f32x8 v) {
    union { bf16v8 h; bf16x8 s; } u;
    u.h = __builtin_convertvector(v, bf16v8);
    return u.s;
}
__device__ __forceinline__ short f2bf1(float f) {
    union { __bf16 h; short s; } u;
    u.h = (__bf16)f;
    return u.s;
}
// v_readlane_b32: VALU->SGPR broadcast, no LDS pipe (vs __shfl = ds_bpermute ~60cyc)
__device__ __forceinline__ float rdlane(float v, int lane) {
    return __uint_as_float(__builtin_amdgcn_readlane(__float_as_uint(v), lane));
}

// ---------------- Pass 1: moments via MFMA, z/gamma staged in LDS once per block.
// grid nblk x 256 (4 waves; wave w owns k-pair {2w,2w+1}). R5-proven structure + cvt8.
__global__ __launch_bounds__(256) void k_moments(const float* __restrict__ z,
                                                 const float* __restrict__ g,
                                                 float* __restrict__ part) {
    __shared__ float zs[64][32];   // 8 KB
    __shared__ float gs[64][8];    // 2 KB
    const int t   = threadIdx.x;
    const int w   = t >> 6;
    const int l   = t & 63;
    const int col = l & 31;
    const int nh  = l >> 5;
    const int k0  = 2 * w;

    f32x16 acc0 = {}, acc1 = {};
    float s1a = 0.f, s1b = 0.f, sga = 0.f, sgb = 0.f;

    for (int c = blockIdx.x; c < NS / 64; c += gridDim.x) {
        const int base = c * 64;
        __syncthreads();   // protect previous iteration's LDS reads
        const float4* zsrc = (const float4*)(z + (size_t)base * 32);
        float4* zdst = (float4*)(&zs[0][0]);
        zdst[t]       = zsrc[t];
        zdst[t + 256] = zsrc[t + 256];
        if (t < 128) {
            ((float4*)(&gs[0][0]))[t] = ((const float4*)(g + (size_t)base * 8))[t];
        }
        __syncthreads();
#pragma unroll
        for (int sc = 0; sc < 4; sc++) {
            const int s0 = sc * 16 + nh * 8;
            f32x8 zv, p0, p1;
#pragma unroll
            for (int j = 0; j < 8; j++) {
                float zf = zs[s0 + j][col];
                float2 gg = *(const float2*)(&gs[s0 + j][k0]);
                zv[j] = zf;
                p0[j] = gg.x * zf;
                p1[j] = gg.y * zf;
                s1a += p0[j];  s1b += p1[j];
                sga += gg.x;   sgb += gg.y;
            }
            bf16x8 af = cvt8(zv), b0 = cvt8(p0), b1 = cvt8(p1);
            acc0 = __builtin_amdgcn_mfma_f32_32x32x16_bf16(af, b0, acc0, 0, 0, 0);
            acc1 = __builtin_amdgcn_mfma_f32_32x32x16_bf16(af, b1, acc1, 0, 0, 0);
        }
    }
    // halves are complementary sample sets; SG is col-duplicated (correct after fold)
    s1a += __shfl_xor(s1a, 32);  s1b += __shfl_xor(s1b, 32);
    sga += __shfl_xor(sga, 32);  sgb += __shfl_xor(sgb, 32);

    float* pb = part + (size_t)blockIdx.x * PART_STRIDE;
#pragma unroll
    for (int r = 0; r < 16; r++) {
        int row = (r & 3) + 8 * (r >> 2) + 4 * nh;   // HW-verified C/D mapping (m74/m101)
        pb[(size_t)k0 * 1024 + row * 32 + col]       = acc0[r];
        pb[(size_t)(k0 + 1) * 1024 + row * 32 + col] = acc1[r];
    }
    if (l < 32) {
        pb[8192 + k0 * 32 + col]       = s1a;   // S1[k0][col]
        pb[8192 + (k0 + 1) * 32 + col] = s1b;
    }
    if (l == 0) { pb[8448 + k0] = sga; pb[8448 + k0 + 1] = sgb; }
}

// ---------------- Reduce partials -> ws S2/S1/SG. Parallel over BOTH axes.
// Also zeroes accumulators, done-counter, and FRAGB region.
__global__ __launch_bounds__(1024) void k_reduce(float* __restrict__ ws, int nblk) {
    __shared__ float red[16][64];
    const int t  = threadIdx.x;
    const int el = t & 63;
    const int bg = t >> 6;
    const int e  = blockIdx.x * 64 + el;
    const float* part = ws + WS_PART;
    float s = 0.0f;
    if (e < PART_STRIDE) {
        for (int b = bg; b < nblk; b += 16)
            s += part[(size_t)b * PART_STRIDE + e];
    }
    red[bg][el] = s;
    __syncthreads();
#pragma unroll
    for (int h = 8; h > 0; h >>= 1) {
        if (bg < h) red[bg][el] += red[bg + h][el];
        __syncthreads();
    }
    if (bg == 0 && e < PART_STRIDE) {
        float v = red[0][el];
        if (e < 8192)       ws[WS_S2 + e] = v;
        else if (e < 8448)  ws[WS_S1 + (e - 8192)] = v;
        else                ws[WS_SG + (e - 8448)] = v;
    }
    if (blockIdx.x == 0) {
        if (t < 512) ws[WS_FRAGB + t] = 0.0f;   // k_prep fills only rows k<8
        if (t == 0) {
            ws[WS_ENERGY] = 0.0f;
            ws[WS_COVDIAG] = 0.0f;
            ((unsigned*)ws)[WS_DONE] = 0u;
        }
    }
}

// ---------------- Pass 2: one single-wave block per matrix (grid = 8 x 64).
// Register-resident Gauss-Jordan on [A | I]; broadcasts via v_readlane (compile-time lanes).
__global__ __launch_bounds__(64) void k_prep(float* __restrict__ ws) {
    __shared__ float Am[32][33];   // Ainv
    __shared__ float mus[32];
    __shared__ float bLs[32];

    const int k   = blockIdx.x;
    const int l   = threadIdx.x;
    const int c32 = l & 31;
    const bool right = l >= 32;

    const float sgk = ws[WS_SG + k];
    if (l < 32) mus[l] = ws[WS_S1 + k * 32 + l] / sgk;
    __syncthreads();
    const float mc  = mus[c32];
    const float rsg = 1.0f / sgk;

    float x[32];
    float dval = 1.0f;
#pragma unroll
    for (int r = 0; r < 32; r++) {
        float v;
        if (right) {
            v = (r == c32) ? 1.0f : 0.0f;
        } else {
            v = ws[WS_S2 + k * 1024 + r * 32 + c32] * rsg - mus[r] * mc;
            if (r == c32) { v += 1.0e-6f + 1.0e-9f; dval = v; }
        }
        x[r] = v;
    }

    // cov_diag partial
    {
        float tdi = right ? 0.0f : 1.0f / dval;
#pragma unroll
        for (int m = 1; m < 64; m <<= 1) tdi += __shfl_xor(tdi, m);
        if (l == 0) atomicAdd(&ws[WS_COVDIAG], tdi);
    }

    // Gauss-Jordan, fully unrolled; pivot broadcasts via v_readlane (lane j is literal)
    float logdet = 0.0f;
#pragma unroll
    for (int j = 0; j < 32; j++) {
        float piv = rdlane(x[j], j);     // A[j][j]
        float rp  = 1.0f / piv;
        logdet += __logf(piv);
        x[j] *= rp;
#pragma unroll
        for (int r = 0; r < 32; r++) {
            if (r == j) continue;
            float m = rdlane(x[r], j);   // A[r][j] (pre-update this pivot)
            x[r] -= m * x[j];
        }
    }
    if (right) {
#pragma unroll
        for (int r = 0; r < 32; r++) Am[r][c32] = x[r];
    }
    __syncthreads();

    // coef_k = phi * exp(-(8*log(2pi) + 0.25*logdet(cov)))
    if (l == 0) {
        float phi = sgk / (float)NS;
        ws[WS_COEF + k] = phi * __expf(-(8.0f * 1.8378770664093453f + 0.25f * logdet));
    }

    // b = Ainv * mu
    if (l < 32) {
        float s = 0.0f;
#pragma unroll
        for (int c = 0; c < 32; c++) s += Am[c32][c] * mus[c];
        bLs[c32] = s;
    }
    __syncthreads();
    // c_k = mu . b
    {
        float cm = (l < 32) ? mus[c32] * bLs[c32] : 0.0f;
#pragma unroll
        for (int m = 1; m < 64; m <<= 1) cm += __shfl_xor(cm, m);
        if (l == 0) ws[WS_C + k] = cm;
    }

    // FRAGA: Ainv bf16 A-operand frags for this k
    {
        const int ph = l >> 5;
#pragma unroll
        for (int h = 0; h < 2; h++) {
            int r = c32, cb = ph * 8 + 16 * h;
            unsigned uu[4];
#pragma unroll
            for (int q = 0; q < 4; q++) {
                unsigned lo2 = (unsigned short)f2bf1(Am[r][cb + 2 * q]);
                unsigned hi2 = (unsigned short)f2bf1(Am[r][cb + 2 * q + 1]);
                uu[q] = lo2 | (hi2 << 16);
            }
            ((uint4*)(ws + WS_FRAGA))[(k * 2 + h) * 64 + l] = make_uint4(uu[0], uu[1], uu[2], uu[3]);
        }
        if (c32 == k) {
#pragma unroll
            for (int h = 0; h < 2; h++) {
                int cb = ph * 8 + 16 * h;
                unsigned uu[4];
#pragma unroll
                for (int q = 0; q < 4; q++) {
                    unsigned lo2 = (unsigned short)f2bf1(bLs[cb + 2 * q]);
                    unsigned hi2 = (unsigned short)f2bf1(bLs[cb + 2 * q + 1]);
                    uu[q] = lo2 | (hi2 << 16);
                }
                ((uint4*)(ws + WS_FRAGB))[h * 64 + l] = make_uint4(uu[0], uu[1], uu[2], uu[3]);
            }
        }
    }
}

// ---------------- Pass 3: energy via MFMA; last block finalizes d_out.
// grid 512 x 512 (8 waves), 2 chunks of 32 samples per wave.
__global__ __launch_bounds__(512) void k_energy(const float* __restrict__ z,
                                                float* __restrict__ ws,
                                                float* __restrict__ out) {
    __shared__ uint4 frg[1152];      // [0,1024): Ainv frags, [1024,1152): b frags
    __shared__ float redw[8];
    const int t   = threadIdx.x;
    const int w   = t >> 6;
    const int l   = t & 63;
    const int col = l & 31;
    const int nh  = l >> 5;

    for (int i = t; i < 1152; i += 512) frg[i] = ((const uint4*)(ws + WS_FRAGA))[i];
    float cf[8], cc[8];
#pragma unroll
    for (int k = 0; k < 8; k++) { cf[k] = ws[WS_COEF + k]; cc[k] = ws[WS_C + k]; }
    __syncthreads();

    float En = 0.0f;
    for (int ci = 0; ci < 2; ci++) {
        const int chunk = (blockIdx.x * 8 + w) * 2 + ci;
        const int n0 = chunk * 32;
        const float* zb = z + (size_t)(n0 + col) * 32 + nh * 8;
        float4 a0 = *(const float4*)(zb + 0);
        float4 a1 = *(const float4*)(zb + 4);
        float4 a2 = *(const float4*)(zb + 16);
        float4 a3 = *(const float4*)(zb + 20);
        f32x8 zlo = {a0.x,a0.y,a0.z,a0.w,a1.x,a1.y,a1.z,a1.w};
        f32x8 zhi = {a2.x,a2.y,a2.z,a2.w,a3.x,a3.y,a3.z,a3.w};
        bf16x8 b0 = cvt8(zlo), b1 = cvt8(zhi);
        float olo[4], ohi[4];
#pragma unroll
        for (int j = 0; j < 4; j++) {
            float mlo = nh ? zlo[j] : zlo[j + 4];
            float mhi = nh ? zhi[j] : zhi[j + 4];
            olo[j] = __shfl_xor(mlo, 32);
            ohi[j] = __shfl_xor(mhi, 32);
        }
        float zdot[16];
#pragma unroll
        for (int j = 0; j < 4; j++) {
            zdot[j]      = nh ? olo[j]     : zlo[j];
            zdot[4 + j]  = nh ? zlo[4 + j] : olo[j];
            zdot[8 + j]  = nh ? ohi[j]     : zhi[j];
            zdot[12 + j] = nh ? zhi[4 + j] : ohi[j];
        }
        f32x16 acc2 = {};
        {
            bf16x8 fb0 = *(const bf16x8*)&frg[1024 + l];
            bf16x8 fb1 = *(const bf16x8*)&frg[1024 + 64 + l];
            acc2 = __builtin_amdgcn_mfma_f32_32x32x16_bf16(fb0, b0, acc2, 0, 0, 0);
            acc2 = __builtin_amdgcn_mfma_f32_32x32x16_bf16(fb1, b1, acc2, 0, 0, 0);
        }
        float oth[4];
#pragma unroll
        for (int r = 0; r < 4; r++) oth[r] = __shfl_xor(acc2[r], 32);
        float pk[8];
#pragma unroll
        for (int k = 0; k < 8; k++) {
            bf16x8 fa0 = *(const bf16x8*)&frg[(k * 2 + 0) * 64 + l];
            bf16x8 fa1 = *(const bf16x8*)&frg[(k * 2 + 1) * 64 + l];
            f32x16 acc = {};
            acc = __builtin_amdgcn_mfma_f32_32x32x16_bf16(fa0, b0, acc, 0, 0, 0);
            acc = __builtin_amdgcn_mfma_f32_32x32x16_bf16(fa1, b1, acc, 0, 0, 0);
            float p = 0.0f;
#pragma unroll
            for (int r = 0; r < 16; r++) p += acc[r] * zdot[r];
            p += __shfl_xor(p, 32);
            pk[k] = p;
        }
        float ssum = 0.0f;
#pragma unroll
        for (int k = 0; k < 8; k++) {
            float d2 = (k < 4) ? (nh ? oth[k] : acc2[k]) : (nh ? acc2[k - 4] : oth[k - 4]);
            float E = pk[k] - 2.0f * d2 + cc[k];
            ssum += cf[k] * __expf(-0.5f * E);
        }
        En += -__logf(ssum + 1.0e-6f);
    }
    // wave reduce (6 shfl steps), then one barrier, then block sum
#pragma unroll
    for (int m = 1; m < 64; m <<= 1) En += __shfl_xor(En, m);
    if (l == 0) redw[w] = En;
    __syncthreads();
    if (t == 0) {
        float s = 0.0f;
#pragma unroll
        for (int i = 0; i < 8; i++) s += redw[i];
        atomicAdd(&ws[WS_ENERGY], s);
        __threadfence();
        unsigned old = atomicAdd((unsigned*)ws + WS_DONE, 1u);
        if (old == gridDim.x - 1) {   // last block finalizes
            float se = atomicAdd(&ws[WS_ENERGY], 0.0f);   // coherent read
            se = se * 0.5f / (float)NS;                   // each sample counted by 2 lane-halves
            if (!isfinite(se)) se = 0.0f;
            float cd = ws[WS_COVDIAG];
            if (!isfinite(cd)) cd = 0.0f;
            out[0] = 0.1f * se + 0.005f * cd;
        }
    }
}

extern "C" void kernel_launch(void* const* d_in, const int* in_sizes, int n_in,
                              void* d_out, int out_size, void* d_ws, size_t ws_size,
                              hipStream_t stream) {
    const float* z = (const float*)d_in[0];
    const float* g = (const float*)d_in[1];
    float* out = (float*)d_out;
    float* ws  = (float*)d_ws;

    long avail = (long)(ws_size / 4) - WS_PART;
    int nblk = (int)(avail / PART_STRIDE);
    if (nblk > 512) nblk = 512;
    if (nblk < 1)   nblk = 1;

    k_moments<<<nblk, 256, 0, stream>>>(z, g, ws + WS_PART);
    k_reduce<<<(PART_STRIDE + 63) / 64, 1024, 0, stream>>>(ws, nblk);
    k_prep<<<8, 64, 0, stream>>>(ws);
    k_energy<<<512, 512, 0, stream>>>(z, ws, out);
}